// Round 1
// baseline (454.421 us; speedup 1.0000x reference)
//
#include <hip/hip_runtime.h>

// ---------------- problem constants ----------------
#define HID   2048
#define NHEAD 16
#define HD    128
#define SEQ   2048
#define BATCH 2
#define MROWS (BATCH*SEQ)        // 4096
#define NQKV  (3*HID)            // 6144
#define INV_NORM 0.08838834764831845f
#define LOG2E    1.4426950408889634f
#define SCALE_L2 (INV_NORM*LOG2E)

typedef __attribute__((ext_vector_type(8)))  __bf16 bf16x8;
typedef __attribute__((ext_vector_type(4)))  float  f32x4;
typedef __attribute__((ext_vector_type(16))) float  f32x16;

typedef __attribute__((address_space(1))) void GV;
typedef __attribute__((address_space(3))) void LV;

__device__ __forceinline__ void async16(const void* g, void* l) {
  __builtin_amdgcn_global_load_lds((const GV*)g, (LV*)l, 16, 0, 0);
}

__device__ __forceinline__ unsigned short f2bf(float f) {
  unsigned u = __builtin_bit_cast(unsigned, f);
  u += 0x7FFFu + ((u >> 16) & 1u);       // RNE
  return (unsigned short)(u >> 16);
}

__device__ __forceinline__ unsigned pkbf(float a, float b) {
#if __has_builtin(__builtin_amdgcn_cvt_pk_bf16_f32)
  typedef __attribute__((ext_vector_type(2))) __bf16 bf16x2;
  bf16x2 r = __builtin_amdgcn_cvt_pk_bf16_f32(a, b);
  return __builtin_bit_cast(unsigned, r);
#else
  return (unsigned)f2bf(a) | ((unsigned)f2bf(b) << 16);
#endif
}

__device__ __forceinline__ void mfma16(f32x4& c, bf16x8 a, bf16x8 b) {
  c = __builtin_amdgcn_mfma_f32_16x16x32_bf16(a, b, c, 0, 0, 0);
}

// LDS fragment read with chunk-XOR swizzle (BK=64 -> 8 chunks of 16B per row)
__device__ __forceinline__ bf16x8 frag(const unsigned short* buf, int row, int chunk) {
  return *(const bf16x8*)(buf + ((row * 8 + (chunk ^ (row & 7))) << 3));
}

// ---------------- fp32 -> bf16 casts ----------------
__global__ __launch_bounds__(256) void cvt_kernel(const float* __restrict__ src,
                                                  unsigned short* __restrict__ dst, int n) {
  int i = (blockIdx.x * 256 + threadIdx.x) * 4;
  if (i >= n) return;
  float4 v = *(const float4*)(src + i);
  ushort4 o;
  o.x = f2bf(v.x); o.y = f2bf(v.y); o.z = f2bf(v.z); o.w = f2bf(v.w);
  *(ushort4*)(dst + i) = o;
}

__global__ __launch_bounds__(256) void cvtw_kernel(const float* __restrict__ W0,
                                                   const float* __restrict__ W1,
                                                   const float* __restrict__ W2,
                                                   const float* __restrict__ W3,
                                                   unsigned short* __restrict__ dst) {
  int sel = blockIdx.y;
  const float* src = (sel == 0) ? W0 : (sel == 1) ? W1 : (sel == 2) ? W2 : W3;
  unsigned short* d = dst + (size_t)sel * HID * HID;
  int i = (blockIdx.x * 256 + threadIdx.x) * 4;
  float4 v = *(const float4*)(src + i);
  ushort4 o;
  o.x = f2bf(v.x); o.y = f2bf(v.y); o.z = f2bf(v.z); o.w = f2bf(v.w);
  *(ushort4*)(d + i) = o;
}

// ---------------- 128x128 NT GEMM core (kept for gemm_out) ----------------
__device__ __forceinline__ void gemm_core(const unsigned short* __restrict__ A,
                                          const unsigned short* __restrict__ Bm,
                                          int K, int m0, int n0,
                                          unsigned short* As, unsigned short* Bs,
                                          f32x4 (&acc)[4][4]) {
  const int tid  = threadIdx.x;
  const int w    = tid >> 6;
  const int lane = tid & 63;
  const int l16  = lane & 15;
  const int quad = lane >> 4;
  const int wm   = (w & 1) * 64;
  const int wn   = (w >> 1) * 64;

  const f32x4 zero = {0.f, 0.f, 0.f, 0.f};
#pragma unroll
  for (int i = 0; i < 4; ++i)
#pragma unroll
    for (int j = 0; j < 4; ++j) acc[i][j] = zero;

  for (int k0 = 0; k0 < K; k0 += 64) {
    __syncthreads();
#pragma unroll
    for (int i = 0; i < 4; ++i) {
      int slot = i * 256 + w * 64 + lane;
      int r = slot >> 3;
      int c = (slot & 7) ^ (r & 7);
      async16(A  + (size_t)(m0 + r) * K + k0 + c * 8, (char*)As + (size_t)(i * 256 + w * 64) * 16);
      async16(Bm + (size_t)(n0 + r) * K + k0 + c * 8, (char*)Bs + (size_t)(i * 256 + w * 64) * 16);
    }
    __syncthreads();

#pragma unroll
    for (int kk = 0; kk < 2; ++kk) {
      bf16x8 af[4], bfp[4];
#pragma unroll
      for (int i = 0; i < 4; ++i) af[i]  = frag(As, wm + i * 16 + l16, kk * 4 + quad);
#pragma unroll
      for (int j = 0; j < 4; ++j) bfp[j] = frag(Bs, wn + j * 16 + l16, kk * 4 + quad);
#pragma unroll
      for (int i = 0; i < 4; ++i)
#pragma unroll
        for (int j = 0; j < 4; ++j) mfma16(acc[i][j], af[i], bfp[j]);
    }
  }
}

// ---------------- GEMM 1: QKV projection, 256x256 8-phase counted-vmcnt ----------------
// 512 thr = 8 waves (2M x 4N); per-wave C = 128x64; BK=64; LDS 128 KiB (2 dbuf x (A+B)).
// buf0 <-> even K-tiles, buf1 <-> odd K-tiles. 2 K-tiles / iteration, 8 phases.
// Per phase: ds_reads || 2x global_load_lds -> s_barrier -> lgkmcnt(0) -> setprio(1)
// + 16 MFMA + setprio(0) -> [vmcnt(2) at P4/P8] -> s_barrier.  vmcnt never drains to 0.
#define ASZ (256 * 64)

__global__ __launch_bounds__(512, 2) void gemm_qkv256_kernel(
    const unsigned short* __restrict__ Xb, const unsigned short* __restrict__ Wb,
    const float* __restrict__ bq, const float* __restrict__ bk,
    const float* __restrict__ bv, unsigned short* __restrict__ Cout) {
  __shared__ __align__(16) unsigned short As[2 * ASZ];   // 64 KiB
  __shared__ __align__(16) unsigned short Bs[2 * ASZ];   // 64 KiB

  const int tid  = threadIdx.x;
  const int w    = tid >> 6;
  const int lane = tid & 63;
  const int l16  = lane & 15;
  const int quad = lane >> 4;
  const int wm   = (w & 1) * 128;
  const int wn   = (w >> 1) * 64;

  // XCD-swizzled tile mapping; grid = 384 = 16(m) x 24(n), 384 % 8 == 0 -> simple bijective
  const int wg = blockIdx.x;
  const int sw = (wg & 7) * 48 + (wg >> 3);
  const int m0 = (sw & 15) * 256;
  const int n0 = (sw >> 4) * 256;

  const unsigned short* Ag = Xb + (size_t)m0 * HID;
  const unsigned short* Bg = Wb + (size_t)n0 * HID;

  // staging: one STG = 512 lanes x 16B = 8 KiB = one 64-row panel; LDS dest linear,
  // global source chunk pre-swizzled (inverse of frag()'s read swizzle)
  const int sr  = tid >> 3;                    // local row 0..63 in panel
  const int scs = ((tid & 7) ^ (sr & 7)) * 8;  // swizzled source chunk offset (ushorts)

#define STG(SRC, DST, RB, KO)                                        \
  async16((SRC) + (size_t)((RB) + sr) * HID + (KO) + scs,            \
          (char*)(DST) + (((RB) * 8 + w * 64) * 16))

  f32x4 acc[8][4];
  const f32x4 zero = {0.f, 0.f, 0.f, 0.f};
#pragma unroll
  for (int a = 0; a < 8; ++a)
#pragma unroll
    for (int j = 0; j < 4; ++j) acc[a][j] = zero;

  // prologue: tile0 -> buf0 (all 4 A + 4 B panels), tile1 A rows{0-63,128-191} -> buf1
  STG(Ag, As, 0, 0);  STG(Ag, As, 64, 0);  STG(Ag, As, 128, 0);  STG(Ag, As, 192, 0);
  STG(Bg, Bs, 0, 0);  STG(Bg, Bs, 64, 0);  STG(Bg, Bs, 128, 0);  STG(Bg, Bs, 192, 0);
  STG(Ag, As + ASZ, 0, 64);  STG(Ag, As + ASZ, 128, 64);
  asm volatile("s_waitcnt vmcnt(2)" ::: "memory");   // buf0 landed; tile1-A1 may fly
  __builtin_amdgcn_s_barrier();

  for (int i = 0; i < 16; ++i) {
    const int k1 = (2 * i + 1) * 64;
    const int t2 = 2 * i + 2, t3 = 2 * i + 3;
    const int k2 = (t2 < 32 ? t2 : 31) * 64;   // clamp: garbage lands in dead buffer
    const int k3 = (t3 < 32 ? t3 : 31) * 64;
    bf16x8 tb0[4], tb1[4];

    // ---- P1: buf0 kk=0 ih=0 | stage A(t1) rows{64,192} -> buf1 ----
    {
      bf16x8 ta[4];
#pragma unroll
      for (int ii = 0; ii < 4; ++ii) ta[ii] = frag(As, wm + ii * 16 + l16, quad);
#pragma unroll
      for (int j = 0; j < 4; ++j) tb0[j] = frag(Bs, wn + j * 16 + l16, quad);
      STG(Ag, As + ASZ, 64, k1);
      STG(Ag, As + ASZ, 192, k1);
      __builtin_amdgcn_s_barrier();
      asm volatile("s_waitcnt lgkmcnt(0)" ::: "memory");
      __builtin_amdgcn_s_setprio(1);
#pragma unroll
      for (int ii = 0; ii < 4; ++ii)
#pragma unroll
        for (int j = 0; j < 4; ++j) mfma16(acc[ii][j], ta[ii], tb0[j]);
      __builtin_amdgcn_s_setprio(0);
      __builtin_amdgcn_s_barrier();
    }
    // ---- P2: buf0 kk=1 ih=0 | stage B(t1) rows{0,64} -> buf1 ----
    {
      bf16x8 ta[4];
#pragma unroll
      for (int ii = 0; ii < 4; ++ii) ta[ii] = frag(As, wm + ii * 16 + l16, 4 + quad);
#pragma unroll
      for (int j = 0; j < 4; ++j) tb1[j] = frag(Bs, wn + j * 16 + l16, 4 + quad);
      STG(Bg, Bs + ASZ, 0, k1);
      STG(Bg, Bs + ASZ, 64, k1);
      __builtin_amdgcn_s_barrier();
      asm volatile("s_waitcnt lgkmcnt(0)" ::: "memory");
      __builtin_amdgcn_s_setprio(1);
#pragma unroll
      for (int ii = 0; ii < 4; ++ii)
#pragma unroll
        for (int j = 0; j < 4; ++j) mfma16(acc[ii][j], ta[ii], tb1[j]);
      __builtin_amdgcn_s_setprio(0);
      __builtin_amdgcn_s_barrier();
    }
    // ---- P3: buf0 kk=0 ih=1 | stage B(t1) rows{128,192} -> buf1 | reuse tb0 ----
    {
      bf16x8 ta[4];
#pragma unroll
      for (int ii = 0; ii < 4; ++ii) ta[ii] = frag(As, wm + 64 + ii * 16 + l16, quad);
      STG(Bg, Bs + ASZ, 128, k1);
      STG(Bg, Bs + ASZ, 192, k1);
      __builtin_amdgcn_s_barrier();
      asm volatile("s_waitcnt lgkmcnt(0)" ::: "memory");
      __builtin_amdgcn_s_setprio(1);
#pragma unroll
      for (int ii = 0; ii < 4; ++ii)
#pragma unroll
        for (int j = 0; j < 4; ++j) mfma16(acc[4 + ii][j], ta[ii], tb0[j]);
      __builtin_amdgcn_s_setprio(0);
      __builtin_amdgcn_s_barrier();
    }
    // ---- P4: buf0 kk=1 ih=1 | stage A(t2) rows{0,128} -> buf0 | reuse tb1 | vmcnt(2) ----
    {
      bf16x8 ta[4];
#pragma unroll
      for (int ii = 0; ii < 4; ++ii) ta[ii] = frag(As, wm + 64 + ii * 16 + l16, 4 + quad);
      STG(Ag, As, 0, k2);
      STG(Ag, As, 128, k2);
      __builtin_amdgcn_s_barrier();
      asm volatile("s_waitcnt lgkmcnt(0)" ::: "memory");
      __builtin_amdgcn_s_setprio(1);
#pragma unroll
      for (int ii = 0; ii < 4; ++ii)
#pragma unroll
        for (int j = 0; j < 4; ++j) mfma16(acc[4 + ii][j], ta[ii], tb1[j]);
      __builtin_amdgcn_s_setprio(0);
      asm volatile("s_waitcnt vmcnt(2)" ::: "memory");  // t1 fully landed in buf1
      __builtin_amdgcn_s_barrier();
    }
    // ---- P5: buf1 kk=0 ih=0 | stage A(t2) rows{64,192} -> buf0 ----
    {
      bf16x8 ta[4];
#pragma unroll
      for (int ii = 0; ii < 4; ++ii) ta[ii] = frag(As + ASZ, wm + ii * 16 + l16, quad);
#pragma unroll
      for (int j = 0; j < 4; ++j) tb0[j] = frag(Bs + ASZ, wn + j * 16 + l16, quad);
      STG(Ag, As, 64, k2);
      STG(Ag, As, 192, k2);
      __builtin_amdgcn_s_barrier();
      asm volatile("s_waitcnt lgkmcnt(0)" ::: "memory");
      __builtin_amdgcn_s_setprio(1);
#pragma unroll
      for (int ii = 0; ii < 4; ++ii)
#pragma unroll
        for (int j = 0; j < 4; ++j) mfma16(acc[ii][j], ta[ii], tb0[j]);
      __builtin_amdgcn_s_setprio(0);
      __builtin_amdgcn_s_barrier();
    }
    // ---- P6: buf1 kk=1 ih=0 | stage B(t2) rows{0,64} -> buf0 ----
    {
      bf16x8 ta[4];
#pragma unroll
      for (int ii = 0; ii < 4; ++ii) ta[ii] = frag(As + ASZ, wm + ii * 16 + l16, 4 + quad);
#pragma unroll
      for (int j = 0; j < 4; ++j) tb1[j] = frag(Bs + ASZ, wn + j * 16 + l16, 4 + quad);
      STG(Bg, Bs, 0, k2);
      STG(Bg, Bs, 64, k2);
      __builtin_amdgcn_s_barrier();
      asm volatile("s_waitcnt lgkmcnt(0)" ::: "memory");
      __builtin_amdgcn_s_setprio(1);
#pragma unroll
      for (int ii = 0; ii < 4; ++ii)
#pragma unroll
        for (int j = 0; j < 4; ++j) mfma16(acc[ii][j], ta[ii], tb1[j]);
      __builtin_amdgcn_s_setprio(0);
      __builtin_amdgcn_s_barrier();
    }
    // ---- P7: buf1 kk=0 ih=1 | stage B(t2) rows{128,192} -> buf0 | reuse tb0 ----
    {
      bf16x8 ta[4];
#pragma unroll
      for (int ii = 0; ii < 4; ++ii) ta[ii] = frag(As + ASZ, wm + 64 + ii * 16 + l16, quad);
      STG(Bg, Bs, 128, k2);
      STG(Bg, Bs, 192, k2);
      __builtin_amdgcn_s_barrier();
      asm volatile("s_waitcnt lgkmcnt(0)" ::: "memory");
      __builtin_amdgcn_s_setprio(1);
#pragma unroll
      for (int ii = 0; ii < 4; ++ii)
#pragma unroll
        for (int j = 0; j < 4; ++j) mfma16(acc[4 + ii][j], ta[ii], tb0[j]);
      __builtin_amdgcn_s_setprio(0);
      __builtin_amdgcn_s_barrier();
    }
    // ---- P8: buf1 kk=1 ih=1 | stage A(t3) rows{0,128} -> buf1 | reuse tb1 | vmcnt(2) ----
    {
      bf16x8 ta[4];
#pragma unroll
      for (int ii = 0; ii < 4; ++ii) ta[ii] = frag(As + ASZ, wm + 64 + ii * 16 + l16, 4 + quad);
      STG(Ag, As + ASZ, 0, k3);
      STG(Ag, As + ASZ, 128, k3);
      __builtin_amdgcn_s_barrier();
      asm volatile("s_waitcnt lgkmcnt(0)" ::: "memory");
      __builtin_amdgcn_s_setprio(1);
#pragma unroll
      for (int ii = 0; ii < 4; ++ii)
#pragma unroll
        for (int j = 0; j < 4; ++j) mfma16(acc[4 + ii][j], ta[ii], tb1[j]);
      __builtin_amdgcn_s_setprio(0);
      asm volatile("s_waitcnt vmcnt(2)" ::: "memory");  // t2 fully landed in buf0
      __builtin_amdgcn_s_barrier();
    }
  }
#undef STG

  // epilogue: bias + bf16 store.  C/D frag: row = quad*4+r, col = l16
#pragma unroll
  for (int j = 0; j < 4; ++j) {
    int ng = n0 + wn + j * 16 + l16;
    float bias = (ng < HID) ? bq[ng] : (ng < 2 * HID ? bk[ng - HID] : bv[ng - 2 * HID]);
#pragma unroll
    for (int a = 0; a < 8; ++a)
#pragma unroll
      for (int r = 0; r < 4; ++r) {
        int mg = m0 + wm + (a >> 2) * 64 + (a & 3) * 16 + quad * 4 + r;
        Cout[(size_t)mg * NQKV + ng] = f2bf(acc[a][j][r] + bias);
      }
  }
}

// ---------------- GEMM 2: out-proj + bias + residual, fp32 out ----------------
__global__ __launch_bounds__(256) void gemm_out_kernel(
    const unsigned short* __restrict__ Ctx, const unsigned short* __restrict__ Wdb,
    const float* __restrict__ bd, const float* __restrict__ Res,
    float* __restrict__ Out) {
  __shared__ __align__(16) unsigned short As[128 * 64];
  __shared__ __align__(16) unsigned short Bs[128 * 64];
  f32x4 acc[4][4];
  const int m0 = blockIdx.y * 128, n0 = blockIdx.x * 128;
  gemm_core(Ctx, Wdb, HID, m0, n0, As, Bs, acc);

  const int tid = threadIdx.x, w = tid >> 6, lane = tid & 63;
  const int l16 = lane & 15, quad = lane >> 4;
  const int wm = (w & 1) * 64, wn = (w >> 1) * 64;
#pragma unroll
  for (int j = 0; j < 4; ++j) {
    int ng = n0 + wn + j * 16 + l16;
    float bias = bd[ng];
#pragma unroll
    for (int i = 0; i < 4; ++i)
#pragma unroll
      for (int r = 0; r < 4; ++r) {
        int mg = m0 + wm + i * 16 + quad * 4 + r;
        size_t off = (size_t)mg * HID + ng;
        Out[off] = acc[i][j][r] + bias + Res[off];
      }
  }
}

// ---------------- V transpose: QKV V-part -> Vt[bh][d][s] ----------------
__global__ __launch_bounds__(256) void vtrans_kernel(const unsigned short* __restrict__ QKV,
                                                     unsigned short* __restrict__ Vt) {
  __shared__ __align__(16) unsigned short T[64][72];
  const int s0 = blockIdx.x * 64, d0 = blockIdx.y * 64, bh = blockIdx.z;
  const int b = bh >> 4, h = bh & 15;
  const int tid = threadIdx.x;
#pragma unroll
  for (int i = 0; i < 2; ++i) {
    int idx = i * 256 + tid;
    int r = idx >> 3, ch = idx & 7;
    const unsigned short* g = QKV + ((size_t)b * SEQ + s0 + r) * NQKV + 2 * HID + h * HD + d0 + ch * 8;
    *(uint4*)(&T[r][ch * 8]) = *(const uint4*)g;
  }
  __syncthreads();
#pragma unroll
  for (int i = 0; i < 2; ++i) {
    int idx = i * 256 + tid;
    int d = idx >> 3, ch = idx & 7;
    unsigned short v[8];
#pragma unroll
    for (int x = 0; x < 8; ++x) v[x] = T[ch * 8 + x][d];
    unsigned short* g = Vt + ((size_t)bh * HD + d0 + d) * SEQ + s0 + ch * 8;
    *(uint4*)g = *(const uint4*)v;
  }
}

// ---------------- flash attention, 32x32 MFMA, S^T trick ----------------
// grid = (SEQ/128, BATCH*NHEAD); block 256 (4 waves, each 32 q-rows)
__global__ __launch_bounds__(256, 2) void attn_kernel(
    const unsigned short* __restrict__ QKV, const unsigned short* __restrict__ Vt,
    const float* __restrict__ alibi, unsigned short* __restrict__ Ctx) {
  __shared__ __align__(16) char smem[51200];
  unsigned short* Ks  = (unsigned short*)smem;
  unsigned short* Vts = (unsigned short*)(smem + 16384);
  unsigned short* Ps  = (unsigned short*)(smem + 32768);
  unsigned short* Qs  = (unsigned short*)smem;          // alias: Q staging (32 KB)

  const int tid = threadIdx.x, w = tid >> 6, lane = tid & 63;
  const int l32 = lane & 31, h = lane >> 5;
  const int q0 = blockIdx.x * 128;
  const int bh = blockIdx.y, b = bh >> 4, hh = bh & 15;
  const size_t rowbase = (size_t)b * SEQ;
  const float* ali = alibi + (size_t)bh * SEQ;
  const unsigned short* Vbh = Vt + (size_t)bh * HD * SEQ;

  {
    const unsigned short* qbase = QKV + (rowbase + q0) * NQKV + hh * HD;
#pragma unroll
    for (int i = 0; i < 8; ++i) {
      int slot = i * 256 + w * 64 + lane;
      int r = slot >> 4, c = (slot & 15) ^ (r & 15);
      async16(qbase + (size_t)r * NQKV + c * 8, (char*)Qs + (size_t)(i * 256 + w * 64) * 16);
    }
  }
  __syncthreads();
  bf16x8 qf[8];
  {
    int qr = w * 32 + l32;
#pragma unroll
    for (int ks = 0; ks < 8; ++ks) {
      int c = (ks * 2 + h) ^ (qr & 15);
      qf[ks] = *(const bf16x8*)(Qs + (qr * 16 + c) * 8);
    }
  }

  f32x16 oacc[4];
  float l_acc = 0.f;
#pragma unroll
  for (int nb = 0; nb < 4; ++nb)
#pragma unroll
    for (int r = 0; r < 16; ++r) oacc[nb][r] = 0.f;

  __syncthreads();

  for (int kt = 0; kt < SEQ / 64; ++kt) {
    {
      const unsigned short* kbase = QKV + (rowbase + kt * 64) * NQKV + HID + hh * HD;
#pragma unroll
      for (int i = 0; i < 4; ++i) {
        int slot = i * 256 + w * 64 + lane;
        int r = slot >> 4, c = (slot & 15) ^ (r & 15);
        async16(kbase + (size_t)r * NQKV + c * 8, (char*)Ks + (size_t)(i * 256 + w * 64) * 16);
      }
      const unsigned short* vbase = Vbh + kt * 64;
#pragma unroll
      for (int i = 0; i < 4; ++i) {
        int slot = i * 256 + w * 64 + lane;
        int r = slot >> 3, c = (slot & 7) ^ (r & 7);
        async16(vbase + (size_t)r * SEQ + c * 8, (char*)Vts + (size_t)(i * 256 + w * 64) * 16);
      }
    }
    __syncthreads();

    f32x16 sacc[2];
#pragma unroll
    for (int mb = 0; mb < 2; ++mb)
#pragma unroll
      for (int r = 0; r < 16; ++r) sacc[mb][r] = 0.f;
#pragma unroll
    for (int ks = 0; ks < 8; ++ks) {
#pragma unroll
      for (int mb = 0; mb < 2; ++mb) {
        bf16x8 kf = *(const bf16x8*)(Ks + ((mb * 32 + l32) * 16 + ((ks * 2 + h) ^ (l32 & 15))) * 8);
        sacc[mb] = __builtin_amdgcn_mfma_f32_32x32x16_bf16(kf, qf[ks], sacc[mb], 0, 0, 0);
      }
    }

    const float* alik = ali + kt * 64 + 4 * h;
    const int qrow = w * 32 + l32;
#pragma unroll
    for (int mb = 0; mb < 2; ++mb) {
#pragma unroll
      for (int g = 0; g < 4; ++g) {
        float4 av = *(const float4*)(alik + mb * 32 + g * 8);
        float p0 = __builtin_amdgcn_exp2f(sacc[mb][g * 4 + 0] * SCALE_L2 + av.x * LOG2E);
        float p1 = __builtin_amdgcn_exp2f(sacc[mb][g * 4 + 1] * SCALE_L2 + av.y * LOG2E);
        float p2 = __builtin_amdgcn_exp2f(sacc[mb][g * 4 + 2] * SCALE_L2 + av.z * LOG2E);
        float p3 = __builtin_amdgcn_exp2f(sacc[mb][g * 4 + 3] * SCALE_L2 + av.w * LOG2E);
        l_acc += (p0 + p1) + (p2 + p3);
        uint2 pk;
        pk.x = pkbf(p0, p1);
        pk.y = pkbf(p2, p3);
        *(uint2*)(Ps + qrow * 72 + mb * 32 + g * 8 + 4 * h) = pk;
      }
    }

#pragma unroll
    for (int ks2 = 0; ks2 < 4; ++ks2) {
      bf16x8 pf = *(const bf16x8*)(Ps + qrow * 72 + ks2 * 16 + h * 8);
#pragma unroll
      for (int nb = 0; nb < 4; ++nb) {
        bf16x8 vf = *(const bf16x8*)(Vts + ((nb * 32 + l32) * 8 + ((ks2 * 2 + h) ^ (l32 & 7))) * 8);
        oacc[nb] = __builtin_amdgcn_mfma_f32_32x32x16_bf16(pf, vf, oacc[nb], 0, 0, 0);
      }
    }
    __syncthreads();
  }

  float lf = l_acc + __shfl_xor(l_acc, 32, 64);
  float rinv[16];
#pragma unroll
  for (int reg = 0; reg < 16; ++reg) {
    int row = (reg & 3) + 8 * (reg >> 2) + 4 * h;
    rinv[reg] = 1.0f / __shfl(lf, row, 64);
  }

#pragma unroll
  for (int nb = 0; nb < 4; ++nb)
#pragma unroll
    for (int reg = 0; reg < 16; ++reg) {
      int row = (reg & 3) + 8 * (reg >> 2) + 4 * h;
      size_t qg = rowbase + q0 + w * 32 + row;
      Ctx[qg * HID + hh * HD + nb * 32 + l32] = f2bf(oacc[nb][reg] * rinv[reg]);
    }
}

// ---------------- launch ----------------
extern "C" void kernel_launch(void* const* d_in, const int* in_sizes, int n_in,
                              void* d_out, int out_size, void* d_ws, size_t ws_size,
                              hipStream_t stream) {
  const float* hidden   = (const float*)d_in[0];
  const float* residual = (const float*)d_in[1];
  const float* alibi    = (const float*)d_in[2];
  const float* Wq = (const float*)d_in[3];
  const float* bq = (const float*)d_in[4];
  const float* Wk = (const float*)d_in[5];
  const float* bk = (const float*)d_in[6];
  const float* Wv = (const float*)d_in[7];
  const float* bv = (const float*)d_in[8];
  const float* Wd = (const float*)d_in[9];
  const float* bd = (const float*)d_in[10];
  float* out = (float*)d_out;

  unsigned short* Xb    = (unsigned short*)d_ws;                    // 4096*2048
  unsigned short* Wqkvb = Xb + (size_t)MROWS * HID;                 // 6144*2048
  unsigned short* Wdb   = Wqkvb + (size_t)NQKV * HID;               // 2048*2048
  unsigned short* QKVb  = Wdb + (size_t)HID * HID;                  // 4096*6144
  unsigned short* Ctxb  = QKVb + (size_t)MROWS * NQKV;              // 4096*2048
  unsigned short* Vtb   = Wqkvb;  // Vt reuses Wqkvb region (dead after gemm_qkv)

  const int nX = MROWS * HID, nW = HID * HID;
  cvt_kernel<<<nX / 4 / 256, 256, 0, stream>>>(hidden, Xb, nX);
  cvtw_kernel<<<dim3(nW / 4 / 256, 4), 256, 0, stream>>>(Wq, Wk, Wv, Wd, Wqkvb);

  gemm_qkv256_kernel<<<384, 512, 0, stream>>>(Xb, Wqkvb, bq, bk, bv, QKVb);
  vtrans_kernel<<<dim3(SEQ / 64, HD / 64, BATCH * NHEAD), 256, 0, stream>>>(QKVb, Vtb);
  attn_kernel<<<dim3(SEQ / 128, BATCH * NHEAD), 256, 0, stream>>>(QKVb, Vtb, alibi, Ctxb);
  gemm_out_kernel<<<dim3(HID / 128, MROWS / 128), 256, 0, stream>>>(Ctxb, Wdb, bd, residual, out);
}